// Round 4
// baseline (27.721 us; speedup 1.0000x reference)
//
#include <hip/hip_runtime.h>
#include <hip/hip_bf16.h>

#define DIM   4096   // 2^12
#define NW    12
#define BATCH 64     // == wavefront size: lane = batch column
#define NBLK  64     // one wave per block; 64 blocks on 256 CUs -> all co-resident

// RX gate [[c, -i s], [-i s, c]] butterfly on complex pair (a0, a1):
//   r0' = c*r0 + s*i1   i0' = c*i0 - s*r1
//   r1' = c*r1 + s*i0   i1' = c*i1 - s*r0
// Wire w acts on row-index bit (11 - w); all wires commute.
//
// Single dispatch. Lane = batch column -> every global access is one
// coalesced 256B wave transaction. Phase 1: block g owns contiguous rows
// [g*64, g*64+64), applies bits 0..5 in registers, stores to out.
// Manual co-resident grid barrier (device-scope atomic in d_ws, reset by a
// captured hipMemsetAsync each call). Phase 2: block g owns rows {hi*64+g},
// applies bits 6..11 in registers, in place.
__global__ __launch_bounds__(64)
void rx_fused(const float* __restrict__ theta,
              const float* __restrict__ xr,
              const float* __restrict__ xi,
              float* out,
              unsigned int* bar) {
    const int g    = blockIdx.x;
    const int lane = threadIdx.x;

    float c[NW], s[NW];
    #pragma unroll
    for (int w = 0; w < NW; ++w) {
        const float t = theta[w];
        c[w] = cosf(t);
        s[w] = sinf(t);
    }

    float* outr = out;
    float* outi = out + DIM * BATCH;

    float vr[64], vi[64];

    // ---------------- Phase 1: bits 0..5 (wires 11..6) ----------------
    const int base = g * 64;
    #pragma unroll
    for (int j = 0; j < 64; ++j) {
        vr[j] = xr[(base + j) * BATCH + lane];
        vi[j] = xi[(base + j) * BATCH + lane];
    }

    #pragma unroll
    for (int k = 0; k < 6; ++k) {
        const float ck = c[11 - k], sk = s[11 - k];
        const int bit = 1 << k, mask = bit - 1;
        #pragma unroll
        for (int p = 0; p < 32; ++p) {
            const int i0 = ((p & ~mask) << 1) | (p & mask);
            const int i1 = i0 | bit;
            const float r0 = vr[i0], m0 = vi[i0];
            const float r1 = vr[i1], m1 = vi[i1];
            vr[i0] = fmaf(ck, r0,  sk * m1);
            vi[i0] = fmaf(ck, m0, -sk * r1);
            vr[i1] = fmaf(ck, r1,  sk * m0);
            vi[i1] = fmaf(ck, m1, -sk * r0);
        }
    }

    #pragma unroll
    for (int j = 0; j < 64; ++j) {
        outr[(base + j) * BATCH + lane] = vr[j];
        outi[(base + j) * BATCH + lane] = vi[j];
    }

    // ---------- co-resident grid barrier (device-scope, cross-XCD) ----------
    __threadfence();                 // release our phase-1 stores device-wide
    __syncthreads();
    if (lane == 0) {
        __hip_atomic_fetch_add(bar, 1u, __ATOMIC_ACQ_REL, __HIP_MEMORY_SCOPE_AGENT);
        while (__hip_atomic_load(bar, __ATOMIC_ACQUIRE, __HIP_MEMORY_SCOPE_AGENT) < NBLK) {
            __builtin_amdgcn_s_sleep(1);
        }
    }
    __syncthreads();
    __threadfence();                 // acquire other blocks' stores

    // ---------------- Phase 2: bits 6..11 (wires 5..0) ----------------
    #pragma unroll
    for (int hi = 0; hi < 64; ++hi) {
        vr[hi] = outr[(hi * 64 + g) * BATCH + lane];
        vi[hi] = outi[(hi * 64 + g) * BATCH + lane];
    }

    #pragma unroll
    for (int j = 0; j < 6; ++j) {            // local bit j == global bit 6+j -> wire 5-j
        const float ck = c[5 - j], sk = s[5 - j];
        const int bit = 1 << j, mask = bit - 1;
        #pragma unroll
        for (int p = 0; p < 32; ++p) {
            const int i0 = ((p & ~mask) << 1) | (p & mask);
            const int i1 = i0 | bit;
            const float r0 = vr[i0], m0 = vi[i0];
            const float r1 = vr[i1], m1 = vi[i1];
            vr[i0] = fmaf(ck, r0,  sk * m1);
            vi[i0] = fmaf(ck, m0, -sk * r1);
            vr[i1] = fmaf(ck, r1,  sk * m0);
            vi[i1] = fmaf(ck, m1, -sk * r0);
        }
    }

    #pragma unroll
    for (int hi = 0; hi < 64; ++hi) {
        outr[(hi * 64 + g) * BATCH + lane] = vr[hi];
        outi[(hi * 64 + g) * BATCH + lane] = vi[hi];
    }
}

extern "C" void kernel_launch(void* const* d_in, const int* in_sizes, int n_in,
                              void* d_out, int out_size, void* d_ws, size_t ws_size,
                              hipStream_t stream) {
    const float* theta = (const float*)d_in[0];  // [12,1]
    const float* xr    = (const float*)d_in[1];  // [4096,64]
    const float* xi    = (const float*)d_in[2];  // [4096,64]
    float*       out   = (float*)d_out;          // [2,4096,64]
    unsigned int* bar  = (unsigned int*)d_ws;    // barrier counter

    // Reset barrier counter every call (graph-capturable async memset).
    hipMemsetAsync(bar, 0, sizeof(unsigned int), stream);
    rx_fused<<<NBLK, 64, 0, stream>>>(theta, xr, xi, out, bar);
}

// Round 5
// 21.859 us; speedup vs baseline: 1.2682x; 1.2682x over previous
//
#include <hip/hip_runtime.h>
#include <hip/hip_bf16.h>

#define DIM   4096   // 2^12 rows
#define NW    12
#define BATCH 64
#define BLKT  1024   // 16 waves

// RX gate U = [[c, -i s], [-i s, c]] is SYMMETRIC: for either element of a
// butterfly pair, out_own = c*own + (-i s)*partner, i.e.
//   r' = c*r_own + s*i_partner
//   i' = c*i_own - s*r_partner
// -> every exchange stage is branch-free.
//
// Wire wi acts on row-bit (11 - wi). Single dispatch, no grid sync:
// block = one batch column; row r = (q<<10)|(w<<6)|lane, thread holds q=0..3.
//   bits 0..5  (wires 11..6): __shfl_xor across lanes
//   bits 6..9  (wires  5..2): LDS exchange across waves
//   bits 10..11(wires  1..0): in-register pair butterflies
__global__ __launch_bounds__(BLKT)
void rx_onepass(const float* __restrict__ theta,
                const float* __restrict__ xr,
                const float* __restrict__ xi,
                float* __restrict__ out) {
    const int col  = blockIdx.x;        // batch column
    const int tid  = threadIdx.x;       // 0..1023
    const int lane = tid & 63;          // row bits 0..5
    const int w    = tid >> 6;          // row bits 6..9

    float c[NW], s[NW];
    #pragma unroll
    for (int wi = 0; wi < NW; ++wi) {
        const float t = theta[wi];
        c[wi] = cosf(t);
        s[wi] = sinf(t);
    }

    const int rbase = (w << 6) | lane;  // row bits 0..9

    float vr[4], vi[4];
    #pragma unroll
    for (int q = 0; q < 4; ++q) {
        const int r = (q << 10) | rbase;
        vr[q] = xr[r * BATCH + col];
        vi[q] = xi[r * BATCH + col];
    }

    // ---- bits 0..5: shuffle butterflies (wire = 11 - k) ----
    #pragma unroll
    for (int k = 0; k < 6; ++k) {
        const float ck = c[11 - k], sk = s[11 - k];
        const int m = 1 << k;
        #pragma unroll
        for (int q = 0; q < 4; ++q) {
            const float pr = __shfl_xor(vr[q], m, 64);
            const float pi = __shfl_xor(vi[q], m, 64);
            vr[q] = fmaf(ck, vr[q],  sk * pi);
            vi[q] = fmaf(ck, vi[q], -sk * pr);
        }
    }

    // ---- bits 6..9: LDS exchange across waves (wire = 5 - j) ----
    __shared__ float lds[8][BLKT];      // SoA: conflict-free, 32 KB
    #pragma unroll
    for (int j = 0; j < 4; ++j) {
        const float ck = c[5 - j], sk = s[5 - j];
        const int pt = tid ^ (1 << (6 + j));   // partner thread (lane bits fixed)
        #pragma unroll
        for (int q = 0; q < 4; ++q) {
            lds[2 * q][tid]     = vr[q];
            lds[2 * q + 1][tid] = vi[q];
        }
        __syncthreads();
        #pragma unroll
        for (int q = 0; q < 4; ++q) {
            const float pr = lds[2 * q][pt];
            const float pi = lds[2 * q + 1][pt];
            vr[q] = fmaf(ck, vr[q],  sk * pi);
            vi[q] = fmaf(ck, vi[q], -sk * pr);
        }
        __syncthreads();
    }

    // ---- bits 10..11: in-register butterflies ----
    // bit 10 -> wire 1: pairs (0,1),(2,3); bit 11 -> wire 0: pairs (0,2),(1,3)
    #pragma unroll
    for (int j = 0; j < 2; ++j) {
        const float ck = c[1 - j], sk = s[1 - j];
        const int bit = 1 << j, mask = bit - 1;
        #pragma unroll
        for (int p = 0; p < 2; ++p) {
            const int a = ((p & ~mask) << 1) | (p & mask);
            const int b = a | bit;
            const float r0 = vr[a], i0 = vi[a];
            const float r1 = vr[b], i1 = vi[b];
            vr[a] = fmaf(ck, r0,  sk * i1);
            vi[a] = fmaf(ck, i0, -sk * r1);
            vr[b] = fmaf(ck, r1,  sk * i0);
            vi[b] = fmaf(ck, i1, -sk * r0);
        }
    }

    float* __restrict__ outr = out;
    float* __restrict__ outi = out + DIM * BATCH;
    #pragma unroll
    for (int q = 0; q < 4; ++q) {
        const int r = (q << 10) | rbase;
        outr[r * BATCH + col] = vr[q];
        outi[r * BATCH + col] = vi[q];
    }
}

extern "C" void kernel_launch(void* const* d_in, const int* in_sizes, int n_in,
                              void* d_out, int out_size, void* d_ws, size_t ws_size,
                              hipStream_t stream) {
    const float* theta = (const float*)d_in[0];  // [12,1]
    const float* xr    = (const float*)d_in[1];  // [4096,64]
    const float* xi    = (const float*)d_in[2];  // [4096,64]
    float*       out   = (float*)d_out;          // [2,4096,64]

    rx_onepass<<<BATCH, BLKT, 0, stream>>>(theta, xr, xi, out);
}

// Round 6
// 14.834 us; speedup vs baseline: 1.8688x; 1.4736x over previous
//
#include <hip/hip_runtime.h>
#include <hip/hip_bf16.h>

#define DIM   4096   // 2^12 rows
#define NW    12
#define BATCH 64     // == wavefront size: lane = batch column

// RX gate U = [[c, -i s], [-i s, c]] is symmetric: for either element of a
// butterfly pair,  r' = c*r_own + s*i_partner ;  i' = c*i_own - s*r_partner.
// Wire wi acts on row-bit (11 - wi); all stages commute.
//
// One generic sweep kernel applies 6 row-bits. Block = 256 threads (4 waves)
// covering one closed 64-row group x 64 batch columns:
//   lane = batch column  -> every global access is one coalesced 256B wave op
//   thread holds 16 rows (group bits 0..3) in registers -> 4 in-reg stages
//   group bits 4..5 are cross-wave -> 2 LDS exchange stages (bank-conflict-free)
// Row addressing: addr = g*GS + j*JS + lane  (phase 1: GS=4096,JS=64;
// phase 2: GS=64,JS=4096).  Stage k uses theta[tbase - k].
__global__ __launch_bounds__(256)
void rx_sweep(const float* __restrict__ theta, int tbase,
              const float* inr, const float* ini,
              float* outr, float* outi,
              int GS, int JS) {
    const int g    = blockIdx.x;     // 0..63: group id
    const int t    = threadIdx.x;    // 0..255
    const int lane = t & 63;         // batch column
    const int w    = t >> 6;         // group bits 4..5

    float c[6], s[6];
    #pragma unroll
    for (int k = 0; k < 6; ++k) {
        const float th = theta[tbase - k];
        c[k] = cosf(th);
        s[k] = sinf(th);
    }

    const int base = g * GS + lane;

    float vr[16], vi[16];
    #pragma unroll
    for (int q = 0; q < 16; ++q) {
        const int j = (w << 4) | q;
        vr[q] = inr[base + j * JS];
        vi[q] = ini[base + j * JS];
    }

    // ---- stages 0..3: in-register pair butterflies over q (group bits 0..3) ----
    #pragma unroll
    for (int k = 0; k < 4; ++k) {
        const float ck = c[k], sk = s[k];
        const int bit = 1 << k, mask = bit - 1;
        #pragma unroll
        for (int p = 0; p < 8; ++p) {
            const int i0 = ((p & ~mask) << 1) | (p & mask);
            const int i1 = i0 | bit;
            const float r0 = vr[i0], m0 = vi[i0];
            const float r1 = vr[i1], m1 = vi[i1];
            vr[i0] = fmaf(ck, r0,  sk * m1);
            vi[i0] = fmaf(ck, m0, -sk * r1);
            vr[i1] = fmaf(ck, r1,  sk * m0);
            vi[i1] = fmaf(ck, m1, -sk * r0);
        }
    }

    // ---- stages 4..5: cross-wave exchange via LDS (group bits 4..5) ----
    // SoA float[64][64]: addr bank = lane%32 -> 2-way aliasing only (free).
    __shared__ float ldr[64][64];
    __shared__ float ldi[64][64];
    #pragma unroll
    for (int k = 4; k < 6; ++k) {
        const float ck = c[k], sk = s[k];
        const int bit = 1 << k;
        #pragma unroll
        for (int q = 0; q < 16; ++q) {
            const int j = (w << 4) | q;
            ldr[j][lane] = vr[q];
            ldi[j][lane] = vi[q];
        }
        __syncthreads();
        #pragma unroll
        for (int q = 0; q < 16; ++q) {
            const int j = ((w << 4) | q) ^ bit;   // partner row (symmetric form)
            const float pr = ldr[j][lane];
            const float pi = ldi[j][lane];
            vr[q] = fmaf(ck, vr[q],  sk * pi);
            vi[q] = fmaf(ck, vi[q], -sk * pr);
        }
        __syncthreads();
    }

    #pragma unroll
    for (int q = 0; q < 16; ++q) {
        const int j = (w << 4) | q;
        outr[base + j * JS] = vr[q];
        outi[base + j * JS] = vi[q];
    }
}

extern "C" void kernel_launch(void* const* d_in, const int* in_sizes, int n_in,
                              void* d_out, int out_size, void* d_ws, size_t ws_size,
                              hipStream_t stream) {
    const float* theta = (const float*)d_in[0];  // [12,1]
    const float* xr    = (const float*)d_in[1];  // [4096,64]
    const float* xi    = (const float*)d_in[2];  // [4096,64]
    float*       outr  = (float*)d_out;          // [4096,64] real
    float*       outi  = outr + DIM * BATCH;     // [4096,64] imag

    // Phase 1: row bits 0..5 (wires 11..6). Block g = rows [g*64, g*64+64).
    //   addr = g*4096 + j*64 + lane;  stage k -> theta[11-k]
    rx_sweep<<<64, 256, 0, stream>>>(theta, 11, xr, xi, outr, outi, 4096, 64);

    // Phase 2: row bits 6..11 (wires 5..0). Block g = rows {j*64 + g}.
    //   addr = j*4096 + g*64 + lane;  stage k -> theta[5-k]   (in place)
    rx_sweep<<<64, 256, 0, stream>>>(theta, 5, outr, outi, outr, outi, 64, 4096);
}

// Round 7
// 14.367 us; speedup vs baseline: 1.9296x; 1.0325x over previous
//
#include <hip/hip_runtime.h>
#include <hip/hip_bf16.h>

#define DIM   4096   // 2^12 rows
#define NW    12
#define BATCH 64

// RX gate U = [[c, -i s], [-i s, c]] is symmetric: for either element of a
// butterfly pair,  r' = c*r_own + s*i_partner ;  i' = c*i_own - s*r_partner.
// Wire wi acts on row-bit (11 - wi); all stages commute.
//
// Generic 6-bit sweep. Grid = 256 blocks (64 row-groups x 4 col-chunks) so all
// 256 CUs are busy. Block = 256 threads (4 waves) covering 64 rows x 16 cols:
//   lane = (rl<<4)|c4 : 16 batch cols x 4 row slots  -> 64B-contiguous loads
//   j (6-bit row-in-group) = (w<<4)|(q<<2)|rl
//     bits 0..1 (rl): __shfl_xor within wave (masks 16, 32)
//     bits 2..3 (q) : in-register pair butterflies (4 rows/thread)
//     bits 4..5 (w) : LDS exchange across the 4 waves
// Row address: addr = g*GS + j*JS + cc*16 + c4
//   phase 1: GS=4096, JS=64  (row = g*64 + j), stage k -> theta[11-k]
//   phase 2: GS=64, JS=4096  (row = j*64 + g), stage k -> theta[5-k]
__global__ __launch_bounds__(256)
void rx_sweep(const float* __restrict__ theta, int tbase,
              const float* inr, const float* ini,
              float* outr, float* outi,
              int GS, int JS) {
    const int bid  = blockIdx.x;
    const int g    = bid >> 2;        // row group 0..63
    const int cc   = bid & 3;         // col chunk 0..3
    const int tid  = threadIdx.x;
    const int lane = tid & 63;
    const int w    = tid >> 6;        // j bits 4..5
    const int c4   = lane & 15;       // col within chunk
    const int rl   = lane >> 4;       // j bits 0..1

    float c[6], s[6];
    #pragma unroll
    for (int k = 0; k < 6; ++k) {
        const float th = theta[tbase - k];
        c[k] = cosf(th);
        s[k] = sinf(th);
    }

    const int base = g * GS + cc * 16 + c4;

    float vr[4], vi[4];
    #pragma unroll
    for (int q = 0; q < 4; ++q) {
        const int j = (w << 4) | (q << 2) | rl;
        vr[q] = inr[base + j * JS];
        vi[q] = ini[base + j * JS];
    }

    // ---- bits 0..1: in-wave shuffle butterflies (symmetric form) ----
    #pragma unroll
    for (int k = 0; k < 2; ++k) {
        const float ck = c[k], sk = s[k];
        const int m = 16 << k;        // lane xor mask: bit0->16, bit1->32
        #pragma unroll
        for (int q = 0; q < 4; ++q) {
            const float pr = __shfl_xor(vr[q], m, 64);
            const float pi = __shfl_xor(vi[q], m, 64);
            vr[q] = fmaf(ck, vr[q],  sk * pi);
            vi[q] = fmaf(ck, vi[q], -sk * pr);
        }
    }

    // ---- bits 2..3: in-register pair butterflies over q ----
    #pragma unroll
    for (int lb = 0; lb < 2; ++lb) {
        const float ck = c[2 + lb], sk = s[2 + lb];
        const int bit = 1 << lb, mask = bit - 1;
        #pragma unroll
        for (int p = 0; p < 2; ++p) {
            const int a = ((p & ~mask) << 1) | (p & mask);
            const int b = a | bit;
            const float r0 = vr[a], m0 = vi[a];
            const float r1 = vr[b], m1 = vi[b];
            vr[a] = fmaf(ck, r0,  sk * m1);
            vi[a] = fmaf(ck, m0, -sk * r1);
            vr[b] = fmaf(ck, r1,  sk * m0);
            vi[b] = fmaf(ck, m1, -sk * r0);
        }
    }

    // ---- bits 4..5: LDS exchange across waves (partner tid ^ 64 / ^ 128) ----
    __shared__ float lds[8][256];     // [2q | 2q+1][tid], 8 KB, conflict-free
    #pragma unroll
    for (int k = 4; k < 6; ++k) {
        const float ck = c[k], sk = s[k];
        const int pt = tid ^ (1 << (2 + k));   // k=4 -> ^64, k=5 -> ^128
        #pragma unroll
        for (int q = 0; q < 4; ++q) {
            lds[2 * q][tid]     = vr[q];
            lds[2 * q + 1][tid] = vi[q];
        }
        __syncthreads();
        #pragma unroll
        for (int q = 0; q < 4; ++q) {
            const float pr = lds[2 * q][pt];
            const float pi = lds[2 * q + 1][pt];
            vr[q] = fmaf(ck, vr[q],  sk * pi);
            vi[q] = fmaf(ck, vi[q], -sk * pr);
        }
        __syncthreads();
    }

    #pragma unroll
    for (int q = 0; q < 4; ++q) {
        const int j = (w << 4) | (q << 2) | rl;
        outr[base + j * JS] = vr[q];
        outi[base + j * JS] = vi[q];
    }
}

extern "C" void kernel_launch(void* const* d_in, const int* in_sizes, int n_in,
                              void* d_out, int out_size, void* d_ws, size_t ws_size,
                              hipStream_t stream) {
    const float* theta = (const float*)d_in[0];  // [12,1]
    const float* xr    = (const float*)d_in[1];  // [4096,64]
    const float* xi    = (const float*)d_in[2];  // [4096,64]
    float*       outr  = (float*)d_out;          // [4096,64] real
    float*       outi  = outr + DIM * BATCH;     // [4096,64] imag

    // Phase 1: row bits 0..5 (wires 11..6): row = g*64 + j.
    rx_sweep<<<256, 256, 0, stream>>>(theta, 11, xr, xi, outr, outi, 4096, 64);

    // Phase 2: row bits 6..11 (wires 5..0): row = j*64 + g, in place.
    rx_sweep<<<256, 256, 0, stream>>>(theta, 5, outr, outi, outr, outi, 64, 4096);
}